// Round 1
// baseline (1163.769 us; speedup 1.0000x reference)
//
#include <hip/hip_runtime.h>
#include <cstddef>
#include <cstdint>

// Problem constants (from reference): B=256, T=512, I=128, H=64, 4H=256.
#define NB 256
#define NT 512
#define H4 256

__device__ __forceinline__ float sigmoid_f(float x) {
    return 1.f / (1.f + __expf(-x));
}
__device__ __forceinline__ float tanh_f(float x) {
    // tanh(x) = 2*sigmoid(2x) - 1; saturates correctly for |x| large.
    return 2.f / (1.f + __expf(-2.f * x)) - 1.f;
}

// ---------------------------------------------------------------------------
// Transpose W [256, K] -> Wt [K, 256] (tiny, once per layer)
// ---------------------------------------------------------------------------
__global__ void transpose_w(const float* __restrict__ W, float* __restrict__ Wt, int K) {
    int idx = blockIdx.x * 256 + threadIdx.x;
    if (idx < 256 * K) {
        int n = idx / K, k = idx - n * K;
        Wt[k * 256 + n] = W[idx];
    }
}

// ---------------------------------------------------------------------------
// Input-projection GEMM: XP[m][n] = sum_k X[m][k]*Wt[k][n] + b1[n] + b2[n]
// M = B*T = 131072, N = 256, K = 128 or 64.
// Tile: 64 rows x 256 cols per workgroup; thread = 16 rows x 4 cols.
// x tile staged transposed in LDS (broadcast reads); Wt staged in 16-k chunks.
// ---------------------------------------------------------------------------
template <int K>
__global__ __launch_bounds__(256) void gemm_xp(
    const float* __restrict__ X, const float* __restrict__ Wt,
    const float* __restrict__ b1, const float* __restrict__ b2,
    float* __restrict__ XP)
{
    constexpr int TM = 64;
    constexpr int KC = 16;
    __shared__ __align__(16) float xT[K][TM + 4];   // +4 pad: 16B-aligned rows, 8-way not 32-way write conflict
    __shared__ __align__(16) float wc[KC][256];
    const int m0 = blockIdx.x * TM;
    const int t  = threadIdx.x;
    const int cg = (t & 63) * 4;     // column base (4 cols per thread)
    const int rg = (t >> 6) * 16;    // row base (16 rows per thread); whole wave shares rg -> LDS broadcast

    // stage x tile transposed: consecutive lanes read consecutive k (coalesced)
    for (int idx = t; idx < TM * K; idx += 256) {
        int r = idx / K, k = idx - r * K;
        xT[k][r] = X[(size_t)(m0 + r) * K + k];
    }

    float acc[16][4];
    #pragma unroll
    for (int i = 0; i < 16; ++i)
        #pragma unroll
        for (int j = 0; j < 4; ++j) acc[i][j] = 0.f;

    for (int kc = 0; kc < K; kc += KC) {
        __syncthreads();   // covers xT staging (first iter) + wc reuse (later iters)
        #pragma unroll
        for (int i = 0; i < 4; ++i) {
            int e4 = (t + i * 256) * 4;
            int k = e4 >> 8, n = e4 & 255;
            *(float4*)&wc[k][n] = *(const float4*)&Wt[(size_t)(kc + k) * 256 + n];
        }
        __syncthreads();
        #pragma unroll
        for (int k = 0; k < KC; ++k) {
            float4 w = *(const float4*)&wc[k][cg];
            float xr[16];
            #pragma unroll
            for (int q = 0; q < 4; ++q)
                *(float4*)&xr[q * 4] = *(const float4*)&xT[kc + k][rg + q * 4];
            #pragma unroll
            for (int rr = 0; rr < 16; ++rr) {
                acc[rr][0] += xr[rr] * w.x;
                acc[rr][1] += xr[rr] * w.y;
                acc[rr][2] += xr[rr] * w.z;
                acc[rr][3] += xr[rr] * w.w;
            }
        }
    }

    float bias[4];
    #pragma unroll
    for (int j = 0; j < 4; ++j) bias[j] = b1[cg + j] + b2[cg + j];
    #pragma unroll
    for (int rr = 0; rr < 16; ++rr) {
        float4 o;
        o.x = acc[rr][0] + bias[0];
        o.y = acc[rr][1] + bias[1];
        o.z = acc[rr][2] + bias[2];
        o.w = acc[rr][3] + bias[3];
        *(float4*)&XP[(size_t)(m0 + rg + rr) * 256 + cg] = o;
    }
}

// ---------------------------------------------------------------------------
// LSTM scan: one workgroup per batch element, 256 threads (thread g = gate g).
// W_hh row g held in registers (64 VGPR). h broadcast via LDS.
// Wave 0: i-gates, wave 1: f, wave 2: g (tanh), wave 3: o -> no divergence.
// Threads 0..63 apply the cell update (c kept in their registers).
// ---------------------------------------------------------------------------
__global__ __launch_bounds__(256) void lstm_scan(
    const float* __restrict__ xp,    // [B*T, 256]
    const float* __restrict__ Whh,   // [256, 64] row-major
    float* __restrict__ hout,        // write_all: [B*T, 64]; else [B, 64] (last t)
    int write_all)
{
    const int b = blockIdx.x;
    const int g = threadIdx.x;
    __shared__ __align__(16) float h_lds[64];
    __shared__ __align__(16) float gl[256];

    // W_hh row into registers (L2-hot: 64KB reused by all 256 wgs)
    float w[64];
    const float4* wrow = (const float4*)(Whh + g * 64);
    #pragma unroll
    for (int q = 0; q < 16; ++q) {
        float4 v = wrow[q];
        w[4*q+0] = v.x; w[4*q+1] = v.y; w[4*q+2] = v.z; w[4*q+3] = v.w;
    }

    float c = 0.f;
    if (g < 64) h_lds[g] = 0.f;
    __syncthreads();

    const float* xpb = xp + (size_t)b * NT * H4;
    float xc = xpb[g];   // t = 0 prefetched

    const bool is_tanh_gate = ((g >> 6) == 2);

    for (int t = 0; t < NT; ++t) {
        // prefetch next timestep's xp (hides HBM latency under the FMA block)
        int tn = (t + 1 < NT) ? (t + 1) : (NT - 1);
        float xn = xpb[(size_t)tn * H4 + g];

        // gates[g] = xp + dot(W_hh[g,:], h)   (4 rotating accumulators for ILP)
        float s[4] = {0.f, 0.f, 0.f, 0.f};
        #pragma unroll
        for (int q = 0; q < 16; ++q) {
            float4 hv = *(const float4*)&h_lds[4 * q];   // broadcast read
            s[q & 3] += w[4*q+0] * hv.x + w[4*q+1] * hv.y
                      + w[4*q+2] * hv.z + w[4*q+3] * hv.w;
        }
        float pre = xc + ((s[0] + s[1]) + (s[2] + s[3]));

        float a = is_tanh_gate ? tanh_f(pre) : sigmoid_f(pre);
        gl[g] = a;
        __syncthreads();

        if (g < 64) {
            float iv = gl[g], fv = gl[64 + g], gv = gl[128 + g], ov = gl[192 + g];
            c = fv * c + iv * gv;
            float h = ov * tanh_f(c);
            h_lds[g] = h;
            if (write_all) {
                hout[((size_t)b * NT + t) * 64 + g] = h;
            } else if (t == NT - 1) {
                hout[(size_t)b * 64 + g] = h;
            }
        }
        __syncthreads();
        xc = xn;
    }
}

// ---------------------------------------------------------------------------
// Final linear: out[b][o] = b_out[o] + sum_j h_last[b][j] * W_out[o][j]
// ---------------------------------------------------------------------------
__global__ __launch_bounds__(256) void final_linear(
    const float* __restrict__ hl,    // [256, 64]
    const float* __restrict__ Wout,  // [2, 64]
    const float* __restrict__ bout,  // [2]
    float* __restrict__ out)         // [256, 2]
{
    __shared__ float w[128];
    int t = threadIdx.x;
    if (t < 128) w[t] = Wout[t];
    __syncthreads();
    const float* h = hl + (size_t)t * 64;
    float a0 = bout[0], a1 = bout[1];
    #pragma unroll 8
    for (int j = 0; j < 64; ++j) {
        float hv = h[j];
        a0 += hv * w[j];
        a1 += hv * w[64 + j];
    }
    out[t * 2 + 0] = a0;
    out[t * 2 + 1] = a1;
}

// ---------------------------------------------------------------------------
extern "C" void kernel_launch(void* const* d_in, const int* in_sizes, int n_in,
                              void* d_out, int out_size, void* d_ws, size_t ws_size,
                              hipStream_t stream)
{
    const float* x     = (const float*)d_in[0];
    const float* W_ih0 = (const float*)d_in[1];
    const float* W_hh0 = (const float*)d_in[2];
    const float* b_ih0 = (const float*)d_in[3];
    const float* b_hh0 = (const float*)d_in[4];
    const float* W_ih1 = (const float*)d_in[5];
    const float* W_hh1 = (const float*)d_in[6];
    const float* b_ih1 = (const float*)d_in[7];
    const float* b_hh1 = (const float*)d_in[8];
    const float* W_ih2 = (const float*)d_in[9];
    const float* W_hh2 = (const float*)d_in[10];
    const float* b_ih2 = (const float*)d_in[11];
    const float* b_hh2 = (const float*)d_in[12];
    const float* W_out = (const float*)d_in[13];
    const float* b_out = (const float*)d_in[14];
    float* out = (float*)d_out;

    const size_t M = (size_t)NB * NT;              // 131072
    const size_t XP_BYTES  = M * H4 * sizeof(float);   // 128 MiB
    const size_t HA_BYTES  = M * 64 * sizeof(float);   // 32 MiB
    const size_t WT0_BYTES = 128 * 256 * sizeof(float);
    const size_t WT1_BYTES = 64 * 256 * sizeof(float);
    const size_t WT2_BYTES = 64 * 256 * sizeof(float);
    const size_t HL_BYTES  = NB * 64 * sizeof(float);
    if (ws_size < XP_BYTES + HA_BYTES + WT0_BYTES + WT1_BYTES + WT2_BYTES + HL_BYTES)
        return;  // workspace too small — fail visibly rather than corrupt memory

    char* ws = (char*)d_ws;
    float* XP  = (float*)ws;
    float* HA  = (float*)(ws + XP_BYTES);
    float* WT0 = (float*)(ws + XP_BYTES + HA_BYTES);
    float* WT1 = WT0 + 128 * 256;
    float* WT2 = WT1 + 64 * 256;
    float* HL  = WT2 + 64 * 256;

    // Pre-transpose input-projection weights
    transpose_w<<<128, 256, 0, stream>>>(W_ih0, WT0, 128);
    transpose_w<<<64, 256, 0, stream>>>(W_ih1, WT1, 64);
    transpose_w<<<64, 256, 0, stream>>>(W_ih2, WT2, 64);

    const int ngrid = (int)(M / 64);   // 2048

    // Layer 0
    gemm_xp<128><<<ngrid, 256, 0, stream>>>(x, WT0, b_ih0, b_hh0, XP);
    lstm_scan<<<NB, 256, 0, stream>>>(XP, W_hh0, HA, 1);
    // Layer 1
    gemm_xp<64><<<ngrid, 256, 0, stream>>>(HA, WT1, b_ih1, b_hh1, XP);
    lstm_scan<<<NB, 256, 0, stream>>>(XP, W_hh1, HA, 1);
    // Layer 2 (only last h needed downstream)
    gemm_xp<64><<<ngrid, 256, 0, stream>>>(HA, WT2, b_ih2, b_hh2, XP);
    lstm_scan<<<NB, 256, 0, stream>>>(XP, W_hh2, HL, 0);
    // Final projection
    final_linear<<<1, 256, 0, stream>>>(HL, W_out, b_out, out);
}